// Round 2
// baseline (273.744 us; speedup 1.0000x reference)
//
#include <hip/hip_runtime.h>
#include <stdint.h>

#define N_ROWS 8192
#define DIM    128
#define NCODES 16384
#define TAU    0.01f
#define MARGIN 0.20f
#define CAP    256

typedef __attribute__((ext_vector_type(4))) float f32x4;
typedef __attribute__((ext_vector_type(8))) short s16x8;

// ---------------- workspace layout (bytes) ----------------
// [0, 2 MiB)        : x_bf16  swizzled (tile-fragment order)
// [2 MiB, 6 MiB)    : cb_bf16 swizzled (tile-fragment order)
// [6 MiB, +32 KiB)  : cnt  int[8192]
// [8 MiB, 16 MiB)   : cand int[8192*256]

__device__ inline unsigned short f2bf(float f) {
    union { float f; unsigned int u; } v; v.f = f;
    unsigned int r = v.u + 0x7FFFu + ((v.u >> 16) & 1u);  // RNE
    return (unsigned short)(r >> 16);
}

__device__ inline void async16(const void* g, void* l) {
    __builtin_amdgcn_global_load_lds(
        (const __attribute__((address_space(1))) void*)g,
        (__attribute__((address_space(3))) void*)l, 16, 0, 0);
}

// ---------------- kernel A: convert + swizzle to fragment order + zero cnt ----------------
// Fragment order: flat = ((tile*4 + kk)*64 + lane)*8 + e
//   where tile = row/16, r = lane&15, q = lane>>4, src = M[tile*16+r][kk*32+q*8+e]
#define XGROUPS  131072   // 8192*128/8
#define CBGROUPS 262144   // 16384*128/8
__global__ void convert_kernel(const float* __restrict__ x, const float* __restrict__ cb,
                               unsigned short* __restrict__ xbf, unsigned short* __restrict__ cbbf,
                               int* __restrict__ cnt) {
    int gid = blockIdx.x * blockDim.x + threadIdx.x;
    if (gid < XGROUPS + CBGROUPS) {
        const float* src; unsigned short* dst; int g;
        if (gid < XGROUPS) { g = gid; src = x; dst = xbf; }
        else               { g = gid - XGROUPS; src = cb; dst = cbbf; }
        const int t = g >> 8, within = g & 255;
        const int kk = within >> 6, ln = within & 63;
        const int r = ln & 15, q = ln >> 4;
        const float* p = src + ((size_t)(t * 16 + r) * DIM + kk * 32 + q * 8);
        s16x8 v;
#pragma unroll
        for (int e = 0; e < 8; ++e) v[e] = (short)f2bf(p[e]);
        *reinterpret_cast<s16x8*>(dst + (size_t)g * 8) = v;
    } else {
        int c = gid - (XGROUPS + CBGROUPS);
        if (c < N_ROWS) cnt[c] = 0;
    }
}

// ---------------- kernel B: async-pipelined bf16 MFMA scores + candidate emission ----------------
// Block: 4 waves, 64 x-rows x 2048 cb rows. Grid = 128 rowgroups x 8 csplits = 1024 blocks.
// Wave owns 32 tiles of 16 cb rows; per-wave 4-deep LDS ring, no barriers in the main loop.
__global__ __launch_bounds__(256, 2) void gemm_topk_kernel(
        const unsigned short* __restrict__ xbf, const unsigned short* __restrict__ cbbf,
        int* __restrict__ cnt, int* __restrict__ cand) {
    __shared__ short smem[4][4][2048];   // [wave][buf][4KB tile]
    __shared__ int rm[64];               // int-punned running row max (block-shared)

    const int wave = threadIdx.x >> 6, lane = threadIdx.x & 63;
    const int r = lane & 15, q = lane >> 4;
    const int rowgrp = blockIdx.x >> 3, csplit = blockIdx.x & 7;
    const int row0 = rowgrp * 64;
    const int tbase = csplit * 128 + wave * 32;

    if (threadIdx.x < 64) rm[threadIdx.x] = (int)0x80000000u;  // -0.0f
    __syncthreads();

    // B fragments (x rows), register-resident for the whole block
    s16x8 bfrag[4][4];
#pragma unroll
    for (int xt = 0; xt < 4; ++xt)
#pragma unroll
        for (int kk = 0; kk < 4; ++kk)
            bfrag[xt][kk] = *reinterpret_cast<const s16x8*>(
                xbf + (((size_t)(rowgrp * 4 + xt) * 4 + kk) * 64 + lane) * 8);

    // prefetch tiles 0..2 into ring bufs 0..2 (4 x 1KB DMA per tile)
#pragma unroll
    for (int p = 0; p < 3; ++p) {
        const unsigned short* g = cbbf + (size_t)(tbase + p) * 2048 + lane * 8;
#pragma unroll
        for (int i = 0; i < 4; ++i) async16(g + i * 512, &smem[wave][p][i * 512]);
    }

    const unsigned ldsbase = (unsigned)(size_t)(&smem[wave][0][0]) + lane * 16;
    float rmv[4] = {-0.f, -0.f, -0.f, -0.f};

#define TILE_BODY(T, WAITN, DODMA)                                                   \
    {                                                                                \
        asm volatile("s_waitcnt vmcnt(%0)" :: "i"(WAITN) : "memory");                \
        s16x8 af[4];                                                                 \
        {                                                                            \
            const unsigned laddr = ldsbase + ((T) & 3) * 4096;                       \
            asm volatile("ds_read_b128 %0, %4 offset:0\n\t"                          \
                         "ds_read_b128 %1, %4 offset:1024\n\t"                       \
                         "ds_read_b128 %2, %4 offset:2048\n\t"                       \
                         "ds_read_b128 %3, %4 offset:3072\n\t"                       \
                         "s_waitcnt lgkmcnt(0)"                                      \
                         : "=&v"(af[0]), "=&v"(af[1]), "=&v"(af[2]), "=&v"(af[3])    \
                         : "v"(laddr) : "memory");                                   \
        }                                                                            \
        f32x4 acc[4];                                                                \
        _Pragma("unroll")                                                            \
        for (int xt = 0; xt < 4; ++xt) acc[xt] = (f32x4){0.f, 0.f, 0.f, 0.f};        \
        _Pragma("unroll")                                                            \
        for (int kk = 0; kk < 4; ++kk)                                               \
            _Pragma("unroll")                                                        \
            for (int xt = 0; xt < 4; ++xt)                                           \
                acc[xt] = __builtin_amdgcn_mfma_f32_16x16x32_bf16(                   \
                    af[kk], bfrag[xt][kk], acc[xt], 0, 0, 0);                        \
        if (DODMA) {                                                                 \
            const unsigned short* g =                                                \
                cbbf + (size_t)(tbase + (T) + 3) * 2048 + lane * 8;                  \
            _Pragma("unroll")                                                        \
            for (int i = 0; i < 4; ++i)                                              \
                async16(g + i * 512, &smem[wave][((T) + 3) & 3][i * 512]);           \
        }                                                                            \
        float mx[4];                                                                 \
        _Pragma("unroll")                                                            \
        for (int xt = 0; xt < 4; ++xt)                                               \
            mx[xt] = fmaxf(fmaxf(acc[xt][0], acc[xt][1]),                            \
                           fmaxf(acc[xt][2], acc[xt][3]));                           \
        const float lmax = fmaxf(fmaxf(mx[0], mx[1]), fmaxf(mx[2], mx[3]));          \
        _Pragma("unroll")                                                            \
        for (int xt = 0; xt < 4; ++xt)                                               \
            if (mx[xt] > rmv[xt]) atomicMax(&rm[xt * 16 + r], __float_as_int(mx[xt]));\
        const float thrmin =                                                         \
            fminf(fminf(rmv[0], rmv[1]), fminf(rmv[2], rmv[3])) - MARGIN;            \
        if (lmax > thrmin) {                                                         \
            _Pragma("unroll")                                                        \
            for (int xt = 0; xt < 4; ++xt) rmv[xt] = __int_as_float(rm[xt * 16 + r]);\
            const int trow = (tbase + (T)) * 16;                                     \
            _Pragma("unroll")                                                        \
            for (int xt = 0; xt < 4; ++xt) {                                         \
                const float thr = rmv[xt] - MARGIN;                                   \
                if (mx[xt] > thr) {                                                  \
                    const int grow = row0 + xt * 16 + r;                             \
                    _Pragma("unroll")                                                \
                    for (int j = 0; j < 4; ++j)                                      \
                        if (acc[xt][j] > thr) {                                      \
                            int pos = atomicAdd(&cnt[grow], 1);                      \
                            if (pos < CAP)                                           \
                                cand[(size_t)grow * CAP + pos] = trow + q * 4 + j;   \
                        }                                                            \
                }                                                                    \
            }                                                                        \
        }                                                                            \
    }

#pragma unroll 1
    for (int t = 0; t < 29; ++t) { TILE_BODY(t, 8, true) }
    TILE_BODY(29, 8, false)
    TILE_BODY(30, 4, false)
    TILE_BODY(31, 0, false)
#undef TILE_BODY
}

// ---------------- kernel C: exact fp32 rescore + top-3 + softmax + combine ----------------
__device__ inline void topk3_insert(float s, int i, float& s1, int& i1,
                                    float& s2, int& i2, float& s3, int& i3) {
    if (s > s1 || (s == s1 && i < i1)) {
        s3 = s2; i3 = i2; s2 = s1; i2 = i1; s1 = s; i1 = i;
    } else if (s > s2 || (s == s2 && i < i2)) {
        s3 = s2; i3 = i2; s2 = s; i2 = i;
    } else if (s > s3 || (s == s3 && i < i3)) {
        s3 = s; i3 = i;
    }
}

__global__ __launch_bounds__(256) void finalize_kernel(
        const float* __restrict__ x, const float* __restrict__ cb,
        const int* __restrict__ cnt, const int* __restrict__ cand,
        float* __restrict__ out) {
    const int lane = threadIdx.x & 63;
    const int row  = blockIdx.x * 4 + (threadIdx.x >> 6);
    const int sub  = lane & 7;   // 8 lanes per candidate, 16 dims each
    const int grp  = lane >> 3;  // 8 candidates in flight

    int c = cnt[row];
    if (c > CAP) c = CAP;
    if (c < 0) c = 0;

    float4 xq[4];
#pragma unroll
    for (int k = 0; k < 4; ++k)
        xq[k] = ((const float4*)x)[(size_t)row * 32 + sub * 4 + k];

    const int BIGI = 0x3FFFFFFF;
    float s1 = -1e30f, s2 = -1e30f, s3 = -1e30f;
    int   i1 = BIGI,   i2 = BIGI,   i3 = BIGI;

    const int rounds = (c + 7) >> 3;
    for (int t = 0; t < rounds; ++t) {
        const int ci  = t * 8 + grp;
        const int idx = (ci < c) ? cand[(size_t)row * CAP + ci] : -1;
        float p = 0.f;
        if (idx >= 0) {
            const float4* cbp = (const float4*)cb + (size_t)idx * 32 + sub * 4;
#pragma unroll
            for (int k = 0; k < 4; ++k) {
                float4 cv = cbp[k];
                p += xq[k].x * cv.x + xq[k].y * cv.y + xq[k].z * cv.z + xq[k].w * cv.w;
            }
        }
        p += __shfl_xor(p, 1);
        p += __shfl_xor(p, 2);
        p += __shfl_xor(p, 4);
        if (idx >= 0) topk3_insert(p, idx, s1, i1, s2, i2, s3, i3);
    }

    float fs1 = -1e30f, fs2 = -1e30f, fs3 = -1e30f;
    int   fi1 = BIGI,   fi2 = BIGI,   fi3 = BIGI;
#pragma unroll
    for (int g = 0; g < 8; ++g) {
        float a1 = __shfl(s1, g * 8); int b1 = __shfl(i1, g * 8);
        float a2 = __shfl(s2, g * 8); int b2 = __shfl(i2, g * 8);
        float a3 = __shfl(s3, g * 8); int b3 = __shfl(i3, g * 8);
        topk3_insert(a1, b1, fs1, fi1, fs2, fi2, fs3, fi3);
        topk3_insert(a2, b2, fs1, fi1, fs2, fi2, fs3, fi3);
        topk3_insert(a3, b3, fs1, fi1, fs2, fi2, fs3, fi3);
    }

    const float m  = fmaxf(fs1, 0.f);
    const float e1 = (fi1 != BIGI) ? __expf((fs1 - m) / TAU) : 0.f;
    const float e2 = (fi2 != BIGI) ? __expf((fs2 - m) / TAU) : 0.f;
    const float e3 = (fi3 != BIGI) ? __expf((fs3 - m) / TAU) : 0.f;
    const float denom = e1 + e2 + e3 + (float)(NCODES - 3) * __expf(-m / TAU);
    const float w1 = e1 / denom, w2 = e2 / denom, w3 = e3 / denom;

    const float2* cb2 = (const float2*)cb;
    float ox = 0.f, oy = 0.f;
    if (fi1 != BIGI) { float2 v = cb2[(size_t)fi1 * 64 + lane]; ox += w1 * v.x; oy += w1 * v.y; }
    if (fi2 != BIGI) { float2 v = cb2[(size_t)fi2 * 64 + lane]; ox += w2 * v.x; oy += w2 * v.y; }
    if (fi3 != BIGI) { float2 v = cb2[(size_t)fi3 * 64 + lane]; ox += w3 * v.x; oy += w3 * v.y; }
    ((float2*)out)[(size_t)row * 64 + lane] = make_float2(ox, oy);
}

// ---------------- launch ----------------
extern "C" void kernel_launch(void* const* d_in, const int* in_sizes, int n_in,
                              void* d_out, int out_size, void* d_ws, size_t ws_size,
                              hipStream_t stream) {
    const float* x  = (const float*)d_in[0];
    const float* cb = (const float*)d_in[1];
    char* ws = (char*)d_ws;

    unsigned short* xbf  = (unsigned short*)ws;                  // 2 MiB
    unsigned short* cbbf = (unsigned short*)(ws + (2u << 20));   // 4 MiB
    int* cnt  = (int*)(ws + (6u << 20));                         // 32 KiB
    int* cand = (int*)(ws + (8u << 20));                         // 8 MiB
    float* out = (float*)d_out;

    hipLaunchKernelGGL(convert_kernel,   dim3(1568), dim3(256), 0, stream, x, cb, xbf, cbbf, cnt);
    hipLaunchKernelGGL(gemm_topk_kernel, dim3(1024), dim3(256), 0, stream, xbf, cbbf, cnt, cand);
    hipLaunchKernelGGL(finalize_kernel,  dim3(2048), dim3(256), 0, stream, x, cb, cnt, cand, out);
}